// Round 5
// baseline (340.311 us; speedup 1.0000x reference)
//
#include <hip/hip_runtime.h>
#include <cstdint>
#include <math.h>

#define NCLS  20
#define MSZ   512
#define DIM   256
#define HW    16384      // 128*128
#define NPIX  131072     // 4 * 2 * 16384
#define AROWS 10240      // NCLS * MSZ
#define TEMP_INV 10.0f
#define EXP2K 14.4269504088896f   // TEMP_INV * log2(e)

typedef __attribute__((ext_vector_type(8))) short bf16x8;
typedef __attribute__((ext_vector_type(4))) float f32x4;

__device__ __forceinline__ short f2bf(float f) {
    unsigned u = __float_as_uint(f);
    unsigned r = (u + 0x7FFFu + ((u >> 16) & 1u)) >> 16;
    return (short)r;
}
__device__ __forceinline__ float bf2f(short s) {
    return __uint_as_float(((unsigned)(unsigned short)s) << 16);
}

// async global->LDS, 16B/lane, wave-uniform LDS base + lane*16
__device__ __forceinline__ void gld16(const void* g, void* l) {
    __builtin_amdgcn_global_load_lds(
        (const __attribute__((address_space(1))) unsigned int*)(uintptr_t)g,
        (__attribute__((address_space(3))) unsigned int*)(unsigned int)(uintptr_t)l,
        16, 0, 0);
}

// ---------------- K1: per-class ordered selection (labels inline) + zero row_sumexp ----------------
__global__ __launch_bounds__(256) void k_select(const int* __restrict__ mg,
                                                const int* __restrict__ ag,
                                                int* __restrict__ sel_idx,
                                                int* __restrict__ counts,
                                                float* __restrict__ row_sumexp) {
    int c = blockIdx.x;
    int t = threadIdx.x;
    // fold the memset node: 20 blocks x 256 threads zero 10240 floats
    for (int i = c * 256 + t; i < AROWS; i += NCLS * 256) row_sumexp[i] = 0.0f;

    int lane = t & 63, wv = t >> 6;
    __shared__ int wcnt[4];
    int base = 0;
    for (int chunk = 0; chunk < NPIX; chunk += 256) {
        int n = chunk + t;
        int b = n >> 15, r = n & 32767;
        const int* g = (r < HW) ? mg : ag;
        int p = (r < HW) ? r : (r - HW);
        int h = p >> 7, w = p & 127;
        int lab = g[(((size_t)b * 512) + (size_t)(h << 2)) * 512 + (size_t)(w << 2)];
        if (lab == 255) lab = -1;
        else if (lab == 254) lab = NCLS - 1;
        bool match = (lab == c);
        unsigned long long mask = __ballot(match);
        if (lane == 0) wcnt[wv] = __popcll(mask);
        __syncthreads();
        int prefix = 0;
#pragma unroll
        for (int i = 0; i < 4; ++i) if (i < wv) prefix += wcnt[i];
        int tot = wcnt[0] + wcnt[1] + wcnt[2] + wcnt[3];
        int rank = base + prefix + __popcll(mask & ((1ull << lane) - 1ull));
        if (match && rank < MSZ) sel_idx[c * MSZ + rank] = n;
        base += tot;
        __syncthreads();
        if (base >= MSZ) break;
    }
    if (t == 0) counts[c] = base;
    for (int r2 = base + t; r2 < MSZ; r2 += 256) sel_idx[c * MSZ + r2] = 0;
}

// ---------------- K2: fused gather+normalize + bank update ----------------
__global__ __launch_bounds__(256) void k_gatherbank(const float* __restrict__ mainp,
                                                    const float* __restrict__ auxp,
                                                    const int* __restrict__ sel_idx,
                                                    const float* __restrict__ bank,
                                                    const int* __restrict__ counts,
                                                    short* __restrict__ anchorsB,
                                                    short* __restrict__ contrasB,
                                                    int* __restrict__ c_valid) {
    int lane = threadIdx.x & 63, wv = threadIdx.x >> 6;
    int a = blockIdx.x * 4 + wv;
    int n = sel_idx[a];
    int b = n >> 15, r = n & 32767;
    const float* src = (r < HW) ? mainp : auxp;
    int p = (r < HW) ? r : (r - HW);
    const float* gsrc = src + (size_t)b * DIM * HW + p;
    float x[4];
#pragma unroll
    for (int q = 0; q < 4; ++q) x[q] = gsrc[(size_t)(lane * 4 + q) * HW];
    float ss = x[0]*x[0] + x[1]*x[1] + x[2]*x[2] + x[3]*x[3];
#pragma unroll
    for (int o = 1; o < 64; o <<= 1) ss += __shfl_xor(ss, o, 64);
    float scale = 1.0f / fmaxf(sqrtf(ss), 1e-12f);
    float ax[4];
#pragma unroll
    for (int q = 0; q < 4; ++q) ax[q] = x[q] * scale;
    short4 oa;
    oa.x = f2bf(ax[0]); oa.y = f2bf(ax[1]); oa.z = f2bf(ax[2]); oa.w = f2bf(ax[3]);
    *(short4*)&anchorsB[(size_t)a * DIM + lane * 4] = oa;

    int cc = a >> 9, m2 = a & 511;
    bool upd = m2 < counts[cc];
    float4 bv = *(const float4*)&bank[(size_t)a * DIM + lane * 4];
    float u[4];
    u[0] = upd ? 0.999f * bv.x + 0.001f * ax[0] : bv.x;
    u[1] = upd ? 0.999f * bv.y + 0.001f * ax[1] : bv.y;
    u[2] = upd ? 0.999f * bv.z + 0.001f * ax[2] : bv.z;
    u[3] = upd ? 0.999f * bv.w + 0.001f * ax[3] : bv.w;
    float ss2 = u[0]*u[0] + u[1]*u[1] + u[2]*u[2] + u[3]*u[3];
#pragma unroll
    for (int o = 1; o < 64; o <<= 1) ss2 += __shfl_xor(ss2, o, 64);
    float nrm = sqrtf(ss2);
    float inv = 1.0f / fmaxf(nrm, 1e-12f);
    short4 oc;
    oc.x = f2bf(upd ? u[0] * inv : bv.x);
    oc.y = f2bf(upd ? u[1] * inv : bv.y);
    oc.z = f2bf(upd ? u[2] * inv : bv.z);
    oc.w = f2bf(upd ? u[3] * inv : bv.w);
    *(short4*)&contrasB[(size_t)a * DIM + lane * 4] = oc;
    if (lane == 0) c_valid[a] = (nrm > 0.0f) ? 1 : 0;
}

// ---------------- K3: bf16 MFMA scores + fused sum-exp ----------------
// 256x256 tile, 512 threads (8 waves 4x2, each 64x128), BK=32 double-buffered,
// global_load_lds prefetch with per-wave vmcnt(4), XOR-swizzled LDS segments.
#define TSM 256
#define TSN 256
__global__ __launch_bounds__(512, 2) void k_score(const short* __restrict__ A,
                                                  const short* __restrict__ Bc,
                                                  const int* __restrict__ c_valid,
                                                  float* __restrict__ row_sumexp) {
    __shared__ short As[2][TSM * 32];   // 32 KB
    __shared__ short Bs[2][TSN * 32];   // 32 KB
    int t = threadIdx.x;
    int lane = t & 63, wv = t >> 6;
    int wr = wv & 3, wc = wv >> 2;        // wave tile: 64 rows x 128 cols
    int row0 = blockIdx.x * TSM, col0 = blockIdx.y * TSN;
    int lrow = lane >> 2;                 // 0..15 row within 16-row chunk
    int gseg = (lane & 3) ^ (lrow & 3);   // swizzled global 16B segment
    int qr = lane >> 4, qc = lane & 15;

    f32x4 acc[4][8] = {};

    const short* Ag = A  + (size_t)row0 * DIM;
    const short* Bg = Bc + (size_t)col0 * DIM;

    auto stage = [&](int buf, int k0) {
#pragma unroll
        for (int g = 0; g < 4; ++g) {
            int f = wv * 4 + g;           // 0..31: chunks of 16 rows (A:0..15, B:16..31)
            if (f < 16) {
                gld16(Ag + (size_t)(f * 16 + lrow) * DIM + k0 + gseg * 8,
                      &As[buf][(f * 16) * 32]);
            } else {
                gld16(Bg + (size_t)((f - 16) * 16 + lrow) * DIM + k0 + gseg * 8,
                      &Bs[buf][((f - 16) * 16) * 32]);
            }
        }
    };

    stage(0, 0);
#pragma unroll
    for (int k = 0; k < 8; ++k) {
        int cur = k & 1;
        if (k < 7) {
            stage(cur ^ 1, (k + 1) * 32);                      // prefetch next
            asm volatile("s_waitcnt vmcnt(4)" ::: "memory");   // only current 4 done
        } else {
            asm volatile("s_waitcnt vmcnt(0)" ::: "memory");
        }
        asm volatile("s_barrier" ::: "memory");

        bf16x8 af[4], bfv[8];
        int slot = (qr ^ (qc & 3)) * 8;
#pragma unroll
        for (int i = 0; i < 4; ++i)
            af[i] = *(const bf16x8*)&As[cur][(wr * 64 + i * 16 + qc) * 32 + slot];
#pragma unroll
        for (int j = 0; j < 8; ++j)
            bfv[j] = *(const bf16x8*)&Bs[cur][(wc * 128 + j * 16 + qc) * 32 + slot];
#pragma unroll
        for (int i = 0; i < 4; ++i)
#pragma unroll
            for (int j = 0; j < 8; ++j)
                acc[i][j] = __builtin_amdgcn_mfma_f32_16x16x32_bf16(af[i], bfv[j], acc[i][j], 0, 0, 0);

        if (k < 7) asm volatile("s_barrier" ::: "memory");     // cur fully read before restage
    }

    // epilogue: per-row sum of exp over valid cols (positives analytic elsewhere)
    float cm[8];
#pragma unroll
    for (int j = 0; j < 8; ++j)
        cm[j] = c_valid[col0 + wc * 128 + j * 16 + qc] ? 1.0f : 0.0f;
#pragma unroll
    for (int i = 0; i < 4; ++i)
#pragma unroll
        for (int r = 0; r < 4; ++r) {
            float e = 0.0f;
#pragma unroll
            for (int j = 0; j < 8; ++j)
                e += cm[j] * exp2f(acc[i][j][r] * EXP2K);
#pragma unroll
            for (int o = 1; o < 16; o <<= 1) e += __shfl_xor(e, o, 64);
            if (qc == 0)
                atomicAdd(&row_sumexp[row0 + wr * 64 + i * 16 + qr * 4 + r], e);
        }
}

// ---------------- K4: per-class S (in LDS) + per-row loss terms -> per-class partials ----------------
__global__ __launch_bounds__(256) void k_classfin(const short* __restrict__ anchorsB,
                                                  const short* __restrict__ contrasB,
                                                  const int* __restrict__ c_valid,
                                                  const int* __restrict__ counts,
                                                  const float* __restrict__ row_sumexp,
                                                  float* __restrict__ cls_loss,
                                                  int* __restrict__ cls_cnt) {
    int c = blockIdx.x, t = threadIdx.x;
    int lane = t & 63, wv = t >> 6;
    __shared__ float Ssh[DIM];
    __shared__ float wls[4];
    __shared__ int wvc[4];
    int base = c * MSZ;

    // phase 1: S[ch] = sum over valid rows (coalesced: 256 threads = one 512B row)
    float s = 0.0f;
    int cnt = 0;
#pragma unroll 4
    for (int m = 0; m < MSZ; ++m) {
        int v = c_valid[base + m];
        float x = bf2f(contrasB[(size_t)(base + m) * DIM + t]);
        s += v ? x : 0.0f;
        cnt += v;
    }
    Ssh[t] = s;
    __syncthreads();
    int pc = cnt;            // identical across threads
    int cc = counts[c];

    // phase 2: per-row terms; 16 lanes per row (4 rows per wave-round)
    int q = lane >> 4, lq = lane & 15;
    float lsum = 0.0f;
    int vc = 0;
    for (int rnd = 0; rnd < MSZ / 16; ++rnd) {
        int m = rnd * 16 + wv * 4 + q;
        int a = base + m;
        const short* ap = &anchorsB[(size_t)a * DIM + lq * 16];
        float dot = 0.0f;
#pragma unroll
        for (int e = 0; e < 16; ++e) dot += bf2f(ap[e]) * Ssh[lq * 16 + e];
#pragma unroll
        for (int o = 1; o < 16; o <<= 1) dot += __shfl_xor(dot, o, 64);
        if (lq == 0 && m < cc && pc > 0) {
            float lse = logf(row_sumexp[a]);
            lsum += (TEMP_INV * dot - (float)pc * lse) / (float)pc;
            vc++;
        }
    }
    // sum the 4 quad-leaders of each wave (other lanes are 0)
#pragma unroll
    for (int o = 16; o < 64; o <<= 1) {
        lsum += __shfl_xor(lsum, o, 64);
        vc   += __shfl_xor(vc, o, 64);
    }
    if (lane == 0) { wls[wv] = lsum; wvc[wv] = vc; }
    __syncthreads();
    if (t == 0) {
        cls_loss[c] = wls[0] + wls[1] + wls[2] + wls[3];
        cls_cnt[c]  = wvc[0] + wvc[1] + wvc[2] + wvc[3];
    }
}

// ---------------- K5: final ----------------
__global__ void k_fin2(const float* __restrict__ cls_loss,
                       const int* __restrict__ cls_cnt,
                       float* __restrict__ out) {
    float L = 0.0f;
    int V = 0;
    for (int c = 0; c < NCLS; ++c) { L += cls_loss[c]; V += cls_cnt[c]; }
    out[0] = -L / (float)(V > 0 ? V : 1);
}

// ---------------- launch ----------------
extern "C" void kernel_launch(void* const* d_in, const int* in_sizes, int n_in,
                              void* d_out, int out_size, void* d_ws, size_t ws_size,
                              hipStream_t stream) {
    const float* main_proj = (const float*)d_in[0];
    const int*   main_gt   = (const int*)d_in[1];
    const float* aux_proj  = (const float*)d_in[2];
    const int*   aux_gt    = (const int*)d_in[3];
    const float* bank      = (const float*)d_in[4];
    float* out = (float*)d_out;

    char* ws = (char*)d_ws;
    int*   sel_idx    = (int*)ws;                    // 40960 B
    int*   counts     = (int*)(ws + 40960);          // 256 B
    int*   c_valid    = (int*)(ws + 41216);          // 40960 B
    float* row_sumexp = (float*)(ws + 82176);        // 40960 B (zeroed by k_select)
    float* cls_loss   = (float*)(ws + 123136);       // 128 B
    int*   cls_cnt    = (int*)(ws + 123264);         // 128 B
    short* anchorsB   = (short*)(ws + 123392);       // 5242880 B
    short* contrasB   = (short*)(ws + 5366272);      // 5242880 B

    k_select<<<NCLS, 256, 0, stream>>>(main_gt, aux_gt, sel_idx, counts, row_sumexp);
    k_gatherbank<<<AROWS / 4, 256, 0, stream>>>(main_proj, aux_proj, sel_idx, bank,
                                                counts, anchorsB, contrasB, c_valid);
    dim3 grid(AROWS / TSM, AROWS / TSN);
    k_score<<<grid, 512, 0, stream>>>(anchorsB, contrasB, c_valid, row_sumexp);
    k_classfin<<<NCLS, 256, 0, stream>>>(anchorsB, contrasB, c_valid, counts,
                                         row_sumexp, cls_loss, cls_cnt);
    k_fin2<<<1, 1, 0, stream>>>(cls_loss, cls_cnt, out);
}

// Round 6
// 332.506 us; speedup vs baseline: 1.0235x; 1.0235x over previous
//
#include <hip/hip_runtime.h>
#include <cstdint>
#include <math.h>

#define NCLS  20
#define MSZ   512
#define DIM   256
#define HW    16384      // 128*128
#define NPIX  131072     // 4 * 2 * 16384
#define AROWS 10240      // NCLS * MSZ
#define TEMP_INV 10.0f
#define EXP2K 14.4269504088896f   // TEMP_INV * log2(e)

typedef __attribute__((ext_vector_type(8))) short bf16x8;
typedef __attribute__((ext_vector_type(4))) float f32x4;

__device__ __forceinline__ short f2bf(float f) {
    unsigned u = __float_as_uint(f);
    unsigned r = (u + 0x7FFFu + ((u >> 16) & 1u)) >> 16;
    return (short)r;
}
__device__ __forceinline__ float bf2f(short s) {
    return __uint_as_float(((unsigned)(unsigned short)s) << 16);
}

// async global->LDS, 16B/lane, wave-uniform LDS base + lane*16
__device__ __forceinline__ void gld16(const void* g, void* l) {
    __builtin_amdgcn_global_load_lds(
        (const __attribute__((address_space(1))) unsigned int*)(uintptr_t)g,
        (__attribute__((address_space(3))) unsigned int*)(unsigned int)(uintptr_t)l,
        16, 0, 0);
}

// ---------------- K1: selection (labels inline) + zero region + pix2row scatter ----------------
__global__ __launch_bounds__(256) void k_select(const int* __restrict__ mg,
                                                const int* __restrict__ ag,
                                                int* __restrict__ sel_idx,
                                                int* __restrict__ counts,
                                                float* __restrict__ zero_region,
                                                int* __restrict__ pix2row) {
    int c = blockIdx.x;
    int t = threadIdx.x;
    // fold memset: zero row_sumexp + S + pcnt (15424 floats)
    for (int i = c * 256 + t; i < 15424; i += NCLS * 256) zero_region[i] = 0.0f;

    int lane = t & 63, wv = t >> 6;
    __shared__ int wcnt[4];
    int base = 0;
    for (int chunk = 0; chunk < NPIX; chunk += 256) {
        int n = chunk + t;
        int b = n >> 15, r = n & 32767;
        const int* g = (r < HW) ? mg : ag;
        int p = (r < HW) ? r : (r - HW);
        int h = p >> 7, w = p & 127;
        int lab = g[(((size_t)b * 512) + (size_t)(h << 2)) * 512 + (size_t)(w << 2)];
        if (lab == 255) lab = -1;
        else if (lab == 254) lab = NCLS - 1;
        bool match = (lab == c);
        unsigned long long mask = __ballot(match);
        if (lane == 0) wcnt[wv] = __popcll(mask);
        __syncthreads();
        int prefix = 0;
#pragma unroll
        for (int i = 0; i < 4; ++i) if (i < wv) prefix += wcnt[i];
        int tot = wcnt[0] + wcnt[1] + wcnt[2] + wcnt[3];
        int rank = base + prefix + __popcll(mask & ((1ull << lane) - 1ull));
        if (match && rank < MSZ) sel_idx[c * MSZ + rank] = n;
        base += tot;
        __syncthreads();
        if (base >= MSZ) break;
    }
    if (t == 0) counts[c] = base;
    int nval = base < MSZ ? base : MSZ;
    for (int r2 = base + t; r2 < MSZ; r2 += 256) sel_idx[c * MSZ + r2] = 0;
    __syncthreads();
    // scatter valid entries into the pixel->row table (pre-memset to -1)
    for (int r2 = t; r2 < nval; r2 += 256)
        pix2row[sel_idx[c * MSZ + r2]] = c * MSZ + r2;
}

// ---------------- K2: coalesced full read of proj, scatter selected to xF ----------------
// thread = (b,src,ch, 4 consecutive pixels); reads are perfectly coalesced.
__global__ __launch_bounds__(256) void k_scatter(const float* __restrict__ mainp,
                                                 const float* __restrict__ auxp,
                                                 const int* __restrict__ pix2row,
                                                 float* __restrict__ xF) {
    int idx = blockIdx.x * 256 + threadIdx.x;   // < 8*256*4096
    int p4 = idx & 4095;
    int ch = (idx >> 12) & 255;
    int bs = idx >> 20;                          // 0..7 = b*2+src
    int b = bs >> 1, src = bs & 1;
    const float* base = (src ? auxp : mainp) + (size_t)b * DIM * HW + (size_t)ch * HW;
    float4 v = *(const float4*)(base + p4 * 4);
    int4 pr = *(const int4*)(pix2row + bs * HW + p4 * 4);
    if (pr.x >= 0) xF[(size_t)pr.x * DIM + ch] = v.x;
    if (pr.y >= 0) xF[(size_t)pr.y * DIM + ch] = v.y;
    if (pr.z >= 0) xF[(size_t)pr.z * DIM + ch] = v.z;
    if (pr.w >= 0) xF[(size_t)pr.w * DIM + ch] = v.w;
}

// ---------------- K3: normalize rows -> bf16 anchors; bank update -> bf16 contras ----------------
__global__ __launch_bounds__(256) void k_normbank(const float* __restrict__ xF,
                                                  const float* __restrict__ bank,
                                                  const int* __restrict__ counts,
                                                  short* __restrict__ anchorsB,
                                                  short* __restrict__ contrasB,
                                                  int* __restrict__ c_valid) {
    int lane = threadIdx.x & 63, wv = threadIdx.x >> 6;
    int a = blockIdx.x * 4 + wv;
    float4 xv = *(const float4*)&xF[(size_t)a * DIM + lane * 4];
    float x[4] = {xv.x, xv.y, xv.z, xv.w};
    float ss = x[0]*x[0] + x[1]*x[1] + x[2]*x[2] + x[3]*x[3];
#pragma unroll
    for (int o = 1; o < 64; o <<= 1) ss += __shfl_xor(ss, o, 64);
    float scale = 1.0f / fmaxf(sqrtf(ss), 1e-12f);
    float ax[4];
#pragma unroll
    for (int q = 0; q < 4; ++q) ax[q] = x[q] * scale;
    short4 oa;
    oa.x = f2bf(ax[0]); oa.y = f2bf(ax[1]); oa.z = f2bf(ax[2]); oa.w = f2bf(ax[3]);
    *(short4*)&anchorsB[(size_t)a * DIM + lane * 4] = oa;

    int cc = a >> 9, m2 = a & 511;
    bool upd = m2 < counts[cc];
    float4 bv = *(const float4*)&bank[(size_t)a * DIM + lane * 4];
    float u[4];
    u[0] = upd ? 0.999f * bv.x + 0.001f * ax[0] : bv.x;
    u[1] = upd ? 0.999f * bv.y + 0.001f * ax[1] : bv.y;
    u[2] = upd ? 0.999f * bv.z + 0.001f * ax[2] : bv.z;
    u[3] = upd ? 0.999f * bv.w + 0.001f * ax[3] : bv.w;
    float ss2 = u[0]*u[0] + u[1]*u[1] + u[2]*u[2] + u[3]*u[3];
#pragma unroll
    for (int o = 1; o < 64; o <<= 1) ss2 += __shfl_xor(ss2, o, 64);
    float nrm = sqrtf(ss2);
    float inv = 1.0f / fmaxf(nrm, 1e-12f);
    short4 oc;
    oc.x = f2bf(upd ? u[0] * inv : bv.x);
    oc.y = f2bf(upd ? u[1] * inv : bv.y);
    oc.z = f2bf(upd ? u[2] * inv : bv.z);
    oc.w = f2bf(upd ? u[3] * inv : bv.w);
    *(short4*)&contrasB[(size_t)a * DIM + lane * 4] = oc;
    if (lane == 0) c_valid[a] = (nrm > 0.0f) ? 1 : 0;
}

// ---------------- K4: per-class sums of valid contras + valid counts ----------------
__global__ __launch_bounds__(256) void k_csum(const short* __restrict__ contrasB,
                                              const int* __restrict__ c_valid,
                                              float* __restrict__ S,
                                              int* __restrict__ pcnt) {
    int c = blockIdx.x >> 2, mg = blockIdx.x & 3;
    int t = threadIdx.x;
    int row0 = c * MSZ + mg * 128;
    float s = 0.0f;
    int cnt = 0;
#pragma unroll 4
    for (int m = 0; m < 128; ++m) {
        int v = c_valid[row0 + m];
        float x = bf2f(contrasB[(size_t)(row0 + m) * DIM + t]);
        s += v ? x : 0.0f;
        cnt += v;
    }
    atomicAdd(&S[c * DIM + t], s);
    if (t == 0) atomicAdd(&pcnt[c], cnt);
}

// ---------------- K5: bf16 MFMA scores + fused sum-exp (R5 structure, unchanged) ----------------
#define TSM 256
#define TSN 256
__global__ __launch_bounds__(512, 2) void k_score(const short* __restrict__ A,
                                                  const short* __restrict__ Bc,
                                                  const int* __restrict__ c_valid,
                                                  float* __restrict__ row_sumexp) {
    __shared__ short As[2][TSM * 32];   // 32 KB
    __shared__ short Bs[2][TSN * 32];   // 32 KB
    int t = threadIdx.x;
    int lane = t & 63, wv = t >> 6;
    int wr = wv & 3, wc = wv >> 2;        // wave tile: 64 rows x 128 cols
    int row0 = blockIdx.x * TSM, col0 = blockIdx.y * TSN;
    int lrow = lane >> 2;
    int gseg = (lane & 3) ^ (lrow & 3);
    int qr = lane >> 4, qc = lane & 15;

    f32x4 acc[4][8] = {};

    const short* Ag = A  + (size_t)row0 * DIM;
    const short* Bg = Bc + (size_t)col0 * DIM;

    auto stage = [&](int buf, int k0) {
#pragma unroll
        for (int g = 0; g < 4; ++g) {
            int f = wv * 4 + g;
            if (f < 16) {
                gld16(Ag + (size_t)(f * 16 + lrow) * DIM + k0 + gseg * 8,
                      &As[buf][(f * 16) * 32]);
            } else {
                gld16(Bg + (size_t)((f - 16) * 16 + lrow) * DIM + k0 + gseg * 8,
                      &Bs[buf][((f - 16) * 16) * 32]);
            }
        }
    };

    stage(0, 0);
#pragma unroll
    for (int k = 0; k < 8; ++k) {
        int cur = k & 1;
        if (k < 7) {
            stage(cur ^ 1, (k + 1) * 32);
            asm volatile("s_waitcnt vmcnt(4)" ::: "memory");
        } else {
            asm volatile("s_waitcnt vmcnt(0)" ::: "memory");
        }
        asm volatile("s_barrier" ::: "memory");

        bf16x8 af[4], bfv[8];
        int slot = (qr ^ (qc & 3)) * 8;
#pragma unroll
        for (int i = 0; i < 4; ++i)
            af[i] = *(const bf16x8*)&As[cur][(wr * 64 + i * 16 + qc) * 32 + slot];
#pragma unroll
        for (int j = 0; j < 8; ++j)
            bfv[j] = *(const bf16x8*)&Bs[cur][(wc * 128 + j * 16 + qc) * 32 + slot];
#pragma unroll
        for (int i = 0; i < 4; ++i)
#pragma unroll
            for (int j = 0; j < 8; ++j)
                acc[i][j] = __builtin_amdgcn_mfma_f32_16x16x32_bf16(af[i], bfv[j], acc[i][j], 0, 0, 0);

        if (k < 7) asm volatile("s_barrier" ::: "memory");
    }

    float cm[8];
#pragma unroll
    for (int j = 0; j < 8; ++j)
        cm[j] = c_valid[col0 + wc * 128 + j * 16 + qc] ? 1.0f : 0.0f;
#pragma unroll
    for (int i = 0; i < 4; ++i)
#pragma unroll
        for (int r = 0; r < 4; ++r) {
            float e = 0.0f;
#pragma unroll
            for (int j = 0; j < 8; ++j)
                e += cm[j] * exp2f(acc[i][j][r] * EXP2K);
#pragma unroll
            for (int o = 1; o < 16; o <<= 1) e += __shfl_xor(e, o, 64);
            if (qc == 0)
                atomicAdd(&row_sumexp[row0 + wr * 64 + i * 16 + qr * 4 + r], e);
        }
}

// ---------------- K6: per-row loss terms (no global atomics) ----------------
__global__ __launch_bounds__(256) void k_fin1(const short* __restrict__ anchorsB,
                                              const float* __restrict__ S,
                                              const int* __restrict__ counts,
                                              const int* __restrict__ pcnt,
                                              const float* __restrict__ row_sumexp,
                                              float* __restrict__ rowterm,
                                              int* __restrict__ rowvld) {
    int lane = threadIdx.x & 63, wv = threadIdx.x >> 6;
    int a = blockIdx.x * 4 + wv;
    int c = a >> 9, m = a & 511;
    short4 a4 = *(const short4*)&anchorsB[(size_t)a * DIM + lane * 4];
    float4 s4 = *(const float4*)&S[c * DIM + lane * 4];
    float dot = bf2f(a4.x) * s4.x + bf2f(a4.y) * s4.y + bf2f(a4.z) * s4.z + bf2f(a4.w) * s4.w;
#pragma unroll
    for (int o = 1; o < 64; o <<= 1) dot += __shfl_xor(dot, o, 64);
    if (lane == 0) {
        int pc = pcnt[c];
        bool va = (m < counts[c]) && (pc > 0);
        float v = 0.0f;
        if (va) {
            float lse = logf(row_sumexp[a]);
            v = (TEMP_INV * dot - (float)pc * lse) / (float)pc;
        }
        rowterm[a] = v;
        rowvld[a] = va ? 1 : 0;
    }
}

// ---------------- K7: final reduction ----------------
__global__ __launch_bounds__(256) void k_fin2(const float* __restrict__ rowterm,
                                              const int* __restrict__ rowvld,
                                              float* __restrict__ out) {
    __shared__ float sred[4];
    __shared__ int cred[4];
    int t = threadIdx.x;
    float lsum = 0.0f;
    int vcnt = 0;
    for (int a = t; a < AROWS; a += 256) {
        lsum += rowterm[a];
        vcnt += rowvld[a];
    }
#pragma unroll
    for (int o = 32; o > 0; o >>= 1) {
        lsum += __shfl_down(lsum, o, 64);
        vcnt += __shfl_down(vcnt, o, 64);
    }
    if ((t & 63) == 0) { sred[t >> 6] = lsum; cred[t >> 6] = vcnt; }
    __syncthreads();
    if (t == 0) {
        float L = sred[0] + sred[1] + sred[2] + sred[3];
        int V = cred[0] + cred[1] + cred[2] + cred[3];
        out[0] = -L / (float)(V > 0 ? V : 1);
    }
}

// ---------------- launch ----------------
extern "C" void kernel_launch(void* const* d_in, const int* in_sizes, int n_in,
                              void* d_out, int out_size, void* d_ws, size_t ws_size,
                              hipStream_t stream) {
    const float* main_proj = (const float*)d_in[0];
    const int*   main_gt   = (const int*)d_in[1];
    const float* aux_proj  = (const float*)d_in[2];
    const int*   aux_gt    = (const int*)d_in[3];
    const float* bank      = (const float*)d_in[4];
    float* out = (float*)d_out;

    char* ws = (char*)d_ws;
    int*   pix2row    = (int*)ws;                    // 524288 B (dead after k_scatter)
    float* rowterm    = (float*)ws;                  // overlay: 40960 B (used from k_fin1)
    int*   rowvld     = (int*)(ws + 40960);          // overlay: 40960 B
    int*   sel_idx    = (int*)(ws + 524288);         // 40960 B
    int*   counts     = (int*)(ws + 565248);         // 256 B
    int*   c_valid    = (int*)(ws + 565504);         // 40960 B
    float* row_sumexp = (float*)(ws + 606464);       // 40960 B  [zero region start]
    float* S          = (float*)(ws + 647424);       // 20480 B
    int*   pcnt       = (int*)(ws + 667904);         // 256 B    [zero region: 15424 floats]
    float* xF         = (float*)(ws + 668160);       // 10485760 B
    short* anchorsB   = (short*)(ws + 11153920);     // 5242880 B
    short* contrasB   = (short*)(ws + 16396800);     // 5242880 B  (end 21639680)

    hipMemsetAsync(pix2row, 0xFF, (size_t)NPIX * 4, stream);   // all -1
    k_select<<<NCLS, 256, 0, stream>>>(main_gt, aux_gt, sel_idx, counts,
                                       row_sumexp, pix2row);
    k_scatter<<<32768, 256, 0, stream>>>(main_proj, aux_proj, pix2row, xF);
    k_normbank<<<AROWS / 4, 256, 0, stream>>>(xF, bank, counts,
                                              anchorsB, contrasB, c_valid);
    k_csum<<<NCLS * 4, 256, 0, stream>>>(contrasB, c_valid, S, pcnt);
    dim3 grid(AROWS / TSM, AROWS / TSN);
    k_score<<<grid, 512, 0, stream>>>(anchorsB, contrasB, c_valid, row_sumexp);
    k_fin1<<<AROWS / 4, 256, 0, stream>>>(anchorsB, S, counts, pcnt, row_sumexp,
                                          rowterm, rowvld);
    k_fin2<<<1, 256, 0, stream>>>(rowterm, rowvld, out);
}

// Round 7
// 298.405 us; speedup vs baseline: 1.1404x; 1.1143x over previous
//
#include <hip/hip_runtime.h>
#include <cstdint>
#include <math.h>

#define NCLS  20
#define MSZ   512
#define DIM   256
#define HW    16384      // 128*128
#define NPIX  131072     // 4 * 2 * 16384
#define AROWS 10240      // NCLS * MSZ
#define TEMP_INV 10.0f
#define EXP2K 14.4269504088896f   // TEMP_INV * log2(e)

typedef __attribute__((ext_vector_type(8))) short bf16x8;
typedef __attribute__((ext_vector_type(4))) float f32x4;

__device__ __forceinline__ short f2bf(float f) {
    unsigned u = __float_as_uint(f);
    unsigned r = (u + 0x7FFFu + ((u >> 16) & 1u)) >> 16;
    return (short)r;
}
__device__ __forceinline__ float bf2f(short s) {
    return __uint_as_float(((unsigned)(unsigned short)s) << 16);
}
// raw transcendental: 2^x in one instruction
__device__ __forceinline__ float fexp2(float x) {
    float r;
    asm volatile("v_exp_f32 %0, %1" : "=v"(r) : "v"(x));
    return r;
}

// async global->LDS, 16B/lane, wave-uniform LDS base + lane*16
__device__ __forceinline__ void gld16(const void* g, void* l) {
    __builtin_amdgcn_global_load_lds(
        (const __attribute__((address_space(1))) unsigned int*)(uintptr_t)g,
        (__attribute__((address_space(3))) unsigned int*)(unsigned int)(uintptr_t)l,
        16, 0, 0);
}

// ---------------- K1: labels + per-chunk class histogram + inits ----------------
__global__ __launch_bounds__(256) void k_hist(const int* __restrict__ mg,
                                              const int* __restrict__ ag,
                                              int* __restrict__ labels,
                                              int* __restrict__ hist,
                                              int* __restrict__ counts,
                                              int* __restrict__ pix2row) {
    int chunk = blockIdx.x, t = threadIdx.x;
    int lane = t & 63;
    int n = chunk * 256 + t;
    int b = n >> 15, r = n & 32767;
    const int* g = (r < HW) ? mg : ag;
    int p = (r < HW) ? r : (r - HW);
    int h = p >> 7, w = p & 127;
    int lab = g[(((size_t)b * 512) + (size_t)(h << 2)) * 512 + (size_t)(w << 2)];
    if (lab == 255) lab = -1;
    else if (lab == 254) lab = NCLS - 1;
    labels[n] = lab;
    pix2row[n] = -1;

    __shared__ int cnt20[NCLS];
    if (t < NCLS) cnt20[t] = 0;
    __syncthreads();
#pragma unroll
    for (int c = 0; c < NCLS; ++c) {
        unsigned long long m = __ballot(lab == c);
        if (lane == 0 && m) atomicAdd(&cnt20[c], __popcll(m));
    }
    __syncthreads();
    if (t < NCLS) {
        hist[t * 512 + chunk] = cnt20[t];
        atomicAdd(&counts[t], cnt20[t]);
    }
}

// ---------------- K2: deterministic ordered compaction -> pix2row ----------------
__global__ __launch_bounds__(256) void k_write(const int* __restrict__ labels,
                                               const int* __restrict__ hist,
                                               int* __restrict__ pix2row) {
    int chunk = blockIdx.x, t = threadIdx.x;
    int lane = t & 63, wv = t >> 6;
    __shared__ int cbase[NCLS];
    __shared__ int wcnt2[4][NCLS];

#pragma unroll
    for (int cc = 0; cc < 5; ++cc) {
        int c = wv * 5 + cc;
        int s = 0;
        for (int j = lane; j < chunk; j += 64) s += hist[c * 512 + j];
#pragma unroll
        for (int o = 32; o > 0; o >>= 1) s += __shfl_down(s, o, 64);
        if (lane == 0) cbase[c] = s;
    }

    int n = chunk * 256 + t;
    int lab = labels[n];
    int myrank = 0;
#pragma unroll
    for (int c = 0; c < NCLS; ++c) {
        unsigned long long m = __ballot(lab == c);
        if (lane == 0) wcnt2[wv][c] = __popcll(m);
        if (lab == c) myrank = __popcll(m & ((1ull << lane) - 1ull));
    }
    __syncthreads();
    if (lab >= 0) {
        int base = cbase[lab] + myrank;
        for (int w = 0; w < wv; ++w) base += wcnt2[w][lab];
        if (base < MSZ) pix2row[n] = lab * MSZ + base;
    }
}

// ---------------- K3: coalesced full read of proj, scatter selected to xF ----------------
__global__ __launch_bounds__(256) void k_scatter(const float* __restrict__ mainp,
                                                 const float* __restrict__ auxp,
                                                 const int* __restrict__ pix2row,
                                                 float* __restrict__ xF) {
    int idx = blockIdx.x * 256 + threadIdx.x;
    int p4 = idx & 4095;
    int ch = (idx >> 12) & 255;
    int bs = idx >> 20;                          // 0..7 = b*2+src
    int b = bs >> 1, src = bs & 1;
    const float* base = (src ? auxp : mainp) + (size_t)b * DIM * HW + (size_t)ch * HW;
    float4 v = *(const float4*)(base + p4 * 4);
    int4 pr = *(const int4*)(pix2row + bs * HW + p4 * 4);
    if (pr.x >= 0) xF[(size_t)pr.x * DIM + ch] = v.x;
    if (pr.y >= 0) xF[(size_t)pr.y * DIM + ch] = v.y;
    if (pr.z >= 0) xF[(size_t)pr.z * DIM + ch] = v.z;
    if (pr.w >= 0) xF[(size_t)pr.w * DIM + ch] = v.w;
}

// ---------------- K4: normalize rows -> bf16 anchors; bank update -> bf16 contras ----------------
__global__ __launch_bounds__(256) void k_normbank(const float* __restrict__ xF,
                                                  const float* __restrict__ bank,
                                                  const int* __restrict__ counts,
                                                  short* __restrict__ anchorsB,
                                                  short* __restrict__ contrasB,
                                                  int* __restrict__ c_valid) {
    int lane = threadIdx.x & 63, wv = threadIdx.x >> 6;
    int a = blockIdx.x * 4 + wv;
    float4 xv = *(const float4*)&xF[(size_t)a * DIM + lane * 4];
    float x[4] = {xv.x, xv.y, xv.z, xv.w};
    float ss = x[0]*x[0] + x[1]*x[1] + x[2]*x[2] + x[3]*x[3];
#pragma unroll
    for (int o = 1; o < 64; o <<= 1) ss += __shfl_xor(ss, o, 64);
    float scale = 1.0f / fmaxf(sqrtf(ss), 1e-12f);
    float ax[4];
#pragma unroll
    for (int q = 0; q < 4; ++q) ax[q] = x[q] * scale;
    short4 oa;
    oa.x = f2bf(ax[0]); oa.y = f2bf(ax[1]); oa.z = f2bf(ax[2]); oa.w = f2bf(ax[3]);
    *(short4*)&anchorsB[(size_t)a * DIM + lane * 4] = oa;

    int cc = a >> 9, m2 = a & 511;
    bool upd = m2 < counts[cc];
    float4 bv = *(const float4*)&bank[(size_t)a * DIM + lane * 4];
    float u[4];
    u[0] = upd ? 0.999f * bv.x + 0.001f * ax[0] : bv.x;
    u[1] = upd ? 0.999f * bv.y + 0.001f * ax[1] : bv.y;
    u[2] = upd ? 0.999f * bv.z + 0.001f * ax[2] : bv.z;
    u[3] = upd ? 0.999f * bv.w + 0.001f * ax[3] : bv.w;
    float ss2 = u[0]*u[0] + u[1]*u[1] + u[2]*u[2] + u[3]*u[3];
#pragma unroll
    for (int o = 1; o < 64; o <<= 1) ss2 += __shfl_xor(ss2, o, 64);
    float nrm = sqrtf(ss2);
    float inv = 1.0f / fmaxf(nrm, 1e-12f);
    short4 oc;
    oc.x = f2bf(upd ? u[0] * inv : bv.x);
    oc.y = f2bf(upd ? u[1] * inv : bv.y);
    oc.z = f2bf(upd ? u[2] * inv : bv.z);
    oc.w = f2bf(upd ? u[3] * inv : bv.w);
    *(short4*)&contrasB[(size_t)a * DIM + lane * 4] = oc;
    if (lane == 0) c_valid[a] = (nrm > 0.0f) ? 1 : 0;
}

// ---------------- K5: per-class sums of valid contras + valid counts (vectorized) ----------------
__global__ __launch_bounds__(256) void k_csum(const short* __restrict__ contrasB,
                                              const int* __restrict__ c_valid,
                                              float* __restrict__ S,
                                              int* __restrict__ pcnt) {
    int c = blockIdx.x >> 3, oct = blockIdx.x & 7;   // 64 rows per octant
    int t = threadIdx.x;
    int rs = t >> 5, cs = t & 31;                    // 8 row-slots x 32 ch-slots (8 ch)
    int row0 = c * MSZ + oct * 64;
    float acc[8] = {0,0,0,0,0,0,0,0};
    int cnt = 0;
#pragma unroll
    for (int m8 = 0; m8 < 8; ++m8) {
        int row = row0 + m8 * 8 + rs;
        int v = c_valid[row];
        bf16x8 x = *(const bf16x8*)&contrasB[(size_t)row * DIM + cs * 8];
        if (v) {
#pragma unroll
            for (int j = 0; j < 8; ++j) acc[j] += bf2f(x[j]);
        }
        if (cs == 0) cnt += v;
    }
    __shared__ float sacc[8][DIM];
    __shared__ int scnt[8];
#pragma unroll
    for (int j = 0; j < 8; ++j) sacc[rs][cs * 8 + j] = acc[j];
    if (cs == 0) scnt[rs] = cnt;
    __syncthreads();
    float s = 0.0f;
#pragma unroll
    for (int r = 0; r < 8; ++r) s += sacc[r][t];
    atomicAdd(&S[c * DIM + t], s);
    if (t == 0) {
        int tot = 0;
#pragma unroll
        for (int r = 0; r < 8; ++r) tot += scnt[r];
        atomicAdd(&pcnt[c], tot);
    }
}

// ---------------- K6: bf16 MFMA scores + fused sum-exp ----------------
#define TSM 256
#define TSN 256
__global__ __launch_bounds__(512, 2) void k_score(const short* __restrict__ A,
                                                  const short* __restrict__ Bc,
                                                  const int* __restrict__ c_valid,
                                                  float* __restrict__ row_sumexp) {
    __shared__ short As[2][TSM * 32];   // 32 KB
    __shared__ short Bs[2][TSN * 32];   // 32 KB
    int t = threadIdx.x;
    int lane = t & 63, wv = t >> 6;
    int wr = wv & 3, wc = wv >> 2;        // wave tile: 64 rows x 128 cols
    int row0 = blockIdx.x * TSM, col0 = blockIdx.y * TSN;
    int lrow = lane >> 2;
    int gseg = (lane & 3) ^ (lrow & 3);
    int qr = lane >> 4, qc = lane & 15;

    f32x4 acc[4][8] = {};

    const short* Ag = A  + (size_t)row0 * DIM;
    const short* Bg = Bc + (size_t)col0 * DIM;

    auto stage = [&](int buf, int k0) {
#pragma unroll
        for (int g = 0; g < 4; ++g) {
            int f = wv * 4 + g;
            if (f < 16) {
                gld16(Ag + (size_t)(f * 16 + lrow) * DIM + k0 + gseg * 8,
                      &As[buf][(f * 16) * 32]);
            } else {
                gld16(Bg + (size_t)((f - 16) * 16 + lrow) * DIM + k0 + gseg * 8,
                      &Bs[buf][((f - 16) * 16) * 32]);
            }
        }
    };

    stage(0, 0);
#pragma unroll
    for (int k = 0; k < 8; ++k) {
        int cur = k & 1;
        if (k < 7) {
            stage(cur ^ 1, (k + 1) * 32);
            asm volatile("s_waitcnt vmcnt(4)" ::: "memory");
        } else {
            asm volatile("s_waitcnt vmcnt(0)" ::: "memory");
        }
        asm volatile("s_barrier" ::: "memory");

        bf16x8 af[4], bfv[8];
        int slot = (qr ^ (qc & 3)) * 8;
#pragma unroll
        for (int i = 0; i < 4; ++i)
            af[i] = *(const bf16x8*)&As[cur][(wr * 64 + i * 16 + qc) * 32 + slot];
#pragma unroll
        for (int j = 0; j < 8; ++j)
            bfv[j] = *(const bf16x8*)&Bs[cur][(wc * 128 + j * 16 + qc) * 32 + slot];
#pragma unroll
        for (int i = 0; i < 4; ++i)
#pragma unroll
            for (int j = 0; j < 8; ++j)
                acc[i][j] = __builtin_amdgcn_mfma_f32_16x16x32_bf16(af[i], bfv[j], acc[i][j], 0, 0, 0);

        if (k < 7) asm volatile("s_barrier" ::: "memory");
    }

    float cm[8];
#pragma unroll
    for (int j = 0; j < 8; ++j)
        cm[j] = c_valid[col0 + wc * 128 + j * 16 + qc] ? 1.0f : 0.0f;
#pragma unroll
    for (int i = 0; i < 4; ++i)
#pragma unroll
        for (int r = 0; r < 4; ++r) {
            float e = 0.0f;
#pragma unroll
            for (int j = 0; j < 8; ++j)
                e += cm[j] * fexp2(acc[i][j][r] * EXP2K);
#pragma unroll
            for (int o = 1; o < 16; o <<= 1) e += __shfl_xor(e, o, 64);
            if (qc == 0)
                atomicAdd(&row_sumexp[row0 + wr * 64 + i * 16 + qr * 4 + r], e);
        }
}

// ---------------- K7: per-row loss terms (no global atomics) ----------------
__global__ __launch_bounds__(256) void k_fin1(const short* __restrict__ anchorsB,
                                              const float* __restrict__ S,
                                              const int* __restrict__ counts,
                                              const int* __restrict__ pcnt,
                                              const float* __restrict__ row_sumexp,
                                              float* __restrict__ rowterm,
                                              int* __restrict__ rowvld) {
    int lane = threadIdx.x & 63, wv = threadIdx.x >> 6;
    int a = blockIdx.x * 4 + wv;
    int c = a >> 9, m = a & 511;
    short4 a4 = *(const short4*)&anchorsB[(size_t)a * DIM + lane * 4];
    float4 s4 = *(const float4*)&S[c * DIM + lane * 4];
    float dot = bf2f(a4.x) * s4.x + bf2f(a4.y) * s4.y + bf2f(a4.z) * s4.z + bf2f(a4.w) * s4.w;
#pragma unroll
    for (int o = 1; o < 64; o <<= 1) dot += __shfl_xor(dot, o, 64);
    if (lane == 0) {
        int pc = pcnt[c];
        bool va = (m < counts[c]) && (pc > 0);
        float v = 0.0f;
        if (va) {
            float lse = logf(row_sumexp[a]);
            v = (TEMP_INV * dot - (float)pc * lse) / (float)pc;
        }
        rowterm[a] = v;
        rowvld[a] = va ? 1 : 0;
    }
}

// ---------------- K8: final reduction ----------------
__global__ __launch_bounds__(256) void k_fin2(const float* __restrict__ rowterm,
                                              const int* __restrict__ rowvld,
                                              float* __restrict__ out) {
    __shared__ float sred[4];
    __shared__ int cred[4];
    int t = threadIdx.x;
    float lsum = 0.0f;
    int vcnt = 0;
    for (int a = t; a < AROWS; a += 256) {
        lsum += rowterm[a];
        vcnt += rowvld[a];
    }
#pragma unroll
    for (int o = 32; o > 0; o >>= 1) {
        lsum += __shfl_down(lsum, o, 64);
        vcnt += __shfl_down(vcnt, o, 64);
    }
    if ((t & 63) == 0) { sred[t >> 6] = lsum; cred[t >> 6] = vcnt; }
    __syncthreads();
    if (t == 0) {
        float L = sred[0] + sred[1] + sred[2] + sred[3];
        int V = cred[0] + cred[1] + cred[2] + cred[3];
        out[0] = -L / (float)(V > 0 ? V : 1);
    }
}

// ---------------- launch ----------------
extern "C" void kernel_launch(void* const* d_in, const int* in_sizes, int n_in,
                              void* d_out, int out_size, void* d_ws, size_t ws_size,
                              hipStream_t stream) {
    const float* main_proj = (const float*)d_in[0];
    const int*   main_gt   = (const int*)d_in[1];
    const float* aux_proj  = (const float*)d_in[2];
    const int*   aux_gt    = (const int*)d_in[3];
    const float* bank      = (const float*)d_in[4];
    float* out = (float*)d_out;

    char* ws = (char*)d_ws;
    int*   labels     = (int*)ws;                    // 524288 B (dead after k_write)
    float* rowterm    = (float*)ws;                  // overlay: 40960 B
    int*   rowvld     = (int*)(ws + 40960);          // overlay: 40960 B
    int*   hist       = (int*)(ws + 524288);         // 40960 B
    int*   pix2row    = (int*)(ws + 565248);         // 524288 B
    int*   c_valid    = (int*)(ws + 1089536);        // 40960 B
    float* row_sumexp = (float*)(ws + 1130496);      // 40960 B  [zero region start]
    float* S          = (float*)(ws + 1171456);      // 20480 B
    int*   pcnt       = (int*)(ws + 1191936);        // 256 B
    int*   counts     = (int*)(ws + 1192192);        // 256 B    [zero region: 61952 B]
    float* xF         = (float*)(ws + 1192448);      // 10485760 B
    short* anchorsB   = (short*)(ws + 11678208);     // 5242880 B
    short* contrasB   = (short*)(ws + 16921088);     // 5242880 B (end 22163968)

    hipMemsetAsync(ws + 1130496, 0, 61952, stream);
    k_hist<<<512, 256, 0, stream>>>(main_gt, aux_gt, labels, hist, counts, pix2row);
    k_write<<<512, 256, 0, stream>>>(labels, hist, pix2row);
    k_scatter<<<32768, 256, 0, stream>>>(main_proj, aux_proj, pix2row, xF);
    k_normbank<<<AROWS / 4, 256, 0, stream>>>(xF, bank, counts,
                                              anchorsB, contrasB, c_valid);
    k_csum<<<NCLS * 8, 256, 0, stream>>>(contrasB, c_valid, S, pcnt);
    dim3 grid(AROWS / TSM, AROWS / TSN);
    k_score<<<grid, 512, 0, stream>>>(anchorsB, contrasB, c_valid, row_sumexp);
    k_fin1<<<AROWS / 4, 256, 0, stream>>>(anchorsB, S, counts, pcnt, row_sumexp,
                                          rowterm, rowvld);
    k_fin2<<<1, 256, 0, stream>>>(rowterm, rowvld, out);
}

// Round 8
// 297.060 us; speedup vs baseline: 1.1456x; 1.0045x over previous
//
#include <hip/hip_runtime.h>
#include <cstdint>
#include <math.h>

#define NCLS  20
#define MSZ   512
#define DIM   256
#define HW    16384      // 128*128
#define NPIX  131072     // 4 * 2 * 16384
#define AROWS 10240      // NCLS * MSZ
#define TEMP_INV 10.0f
#define EXP2K 14.4269504088896f   // TEMP_INV * log2(e)

typedef __attribute__((ext_vector_type(8))) short bf16x8;
typedef __attribute__((ext_vector_type(4))) float f32x4;

__device__ __forceinline__ short f2bf(float f) {
    unsigned u = __float_as_uint(f);
    unsigned r = (u + 0x7FFFu + ((u >> 16) & 1u)) >> 16;
    return (short)r;
}
__device__ __forceinline__ float bf2f(short s) {
    return __uint_as_float(((unsigned)(unsigned short)s) << 16);
}
__device__ __forceinline__ float fexp2(float x) {
    float r;
    asm volatile("v_exp_f32 %0, %1" : "=v"(r) : "v"(x));
    return r;
}
// async global->LDS, 16B/lane, wave-uniform LDS base + lane*16
__device__ __forceinline__ void gld16(const void* g, void* l) {
    __builtin_amdgcn_global_load_lds(
        (const __attribute__((address_space(1))) unsigned int*)(uintptr_t)g,
        (__attribute__((address_space(3))) unsigned int*)(unsigned int)(uintptr_t)l,
        16, 0, 0);
}

// zero-region float layout (15488 floats = 61952 B):
//   [0]       row_sumexp   (10240)
//   [10240]   S            (5120)
//   [15360]   pcnt         (20 ints)
//   [15380]   facc[2]      (loss sum, valid count)
//   [15382]   done_cnt     (int)
#define ZREG_FLOATS 15488

// ---------------- K1: labels + per-chunk class histogram + inits (no cross-block races) ----------------
__global__ __launch_bounds__(256) void k_hist(const int* __restrict__ mg,
                                              const int* __restrict__ ag,
                                              int* __restrict__ labels,
                                              int* __restrict__ hist,
                                              int* __restrict__ pix2row,
                                              float* __restrict__ zreg) {
    int chunk = blockIdx.x, t = threadIdx.x;
    int lane = t & 63;
    int gi = chunk * 256 + t;
    if (gi < ZREG_FLOATS) zreg[gi] = 0.0f;

    int n = gi;
    int b = n >> 15, r = n & 32767;
    const int* g = (r < HW) ? mg : ag;
    int p = (r < HW) ? r : (r - HW);
    int h = p >> 7, w = p & 127;
    int lab = g[(((size_t)b * 512) + (size_t)(h << 2)) * 512 + (size_t)(w << 2)];
    if (lab == 255) lab = -1;
    else if (lab == 254) lab = NCLS - 1;
    labels[n] = lab;
    pix2row[n] = -1;

    __shared__ int cnt20[NCLS];
    if (t < NCLS) cnt20[t] = 0;
    __syncthreads();
#pragma unroll
    for (int c = 0; c < NCLS; ++c) {
        unsigned long long m = __ballot(lab == c);
        if (lane == 0 && m) atomicAdd(&cnt20[c], __popcll(m));
    }
    __syncthreads();
    if (t < NCLS) hist[t * 512 + chunk] = cnt20[t];
}

// ---------------- K2: deterministic ordered compaction -> pix2row; last chunk writes counts ----------------
__global__ __launch_bounds__(256) void k_write(const int* __restrict__ labels,
                                               const int* __restrict__ hist,
                                               int* __restrict__ pix2row,
                                               int* __restrict__ counts) {
    int chunk = blockIdx.x, t = threadIdx.x;
    int lane = t & 63, wv = t >> 6;
    __shared__ int cbase[NCLS];
    __shared__ int wcnt2[4][NCLS];

#pragma unroll
    for (int cc = 0; cc < 5; ++cc) {
        int c = wv * 5 + cc;
        int s = 0;
        for (int j = lane; j < chunk; j += 64) s += hist[c * 512 + j];
#pragma unroll
        for (int o = 32; o > 0; o >>= 1) s += __shfl_down(s, o, 64);
        if (lane == 0) cbase[c] = s;
    }

    int n = chunk * 256 + t;
    int lab = labels[n];
    int myrank = 0;
#pragma unroll
    for (int c = 0; c < NCLS; ++c) {
        unsigned long long m = __ballot(lab == c);
        if (lane == 0) wcnt2[wv][c] = __popcll(m);
        if (lab == c) myrank = __popcll(m & ((1ull << lane) - 1ull));
    }
    __syncthreads();
    if (lab >= 0) {
        int base = cbase[lab] + myrank;
        for (int w = 0; w < wv; ++w) base += wcnt2[w][lab];
        if (base < MSZ) pix2row[n] = lab * MSZ + base;
    }
    // chunk 511: total count per class = prefix + own chunk (race-free, no atomics)
    if (chunk == 511 && t < NCLS)
        counts[t] = cbase[t] + wcnt2[0][t] + wcnt2[1][t] + wcnt2[2][t] + wcnt2[3][t];
}

// ---------------- K3: coalesced full read of proj, scatter selected to xF ----------------
__global__ __launch_bounds__(256) void k_scatter(const float* __restrict__ mainp,
                                                 const float* __restrict__ auxp,
                                                 const int* __restrict__ pix2row,
                                                 float* __restrict__ xF) {
    int idx = blockIdx.x * 256 + threadIdx.x;
    int p4 = idx & 4095;
    int ch = (idx >> 12) & 255;
    int bs = idx >> 20;                          // 0..7 = b*2+src
    int b = bs >> 1, src = bs & 1;
    const float* base = (src ? auxp : mainp) + (size_t)b * DIM * HW + (size_t)ch * HW;
    float4 v = *(const float4*)(base + p4 * 4);
    int4 pr = *(const int4*)(pix2row + bs * HW + p4 * 4);
    if (pr.x >= 0) xF[(size_t)pr.x * DIM + ch] = v.x;
    if (pr.y >= 0) xF[(size_t)pr.y * DIM + ch] = v.y;
    if (pr.z >= 0) xF[(size_t)pr.z * DIM + ch] = v.z;
    if (pr.w >= 0) xF[(size_t)pr.w * DIM + ch] = v.w;
}

// ---------------- K4: fused normalize + bank update + per-class S/pcnt ----------------
// block = 64 rows of one class (160 blocks); wave handles 16 rows (4 consecutive rows / iter)
__global__ __launch_bounds__(256) void k_nbc(const float* __restrict__ xF,
                                             const float* __restrict__ bank,
                                             const int* __restrict__ counts,
                                             short* __restrict__ anchorsB,
                                             short* __restrict__ contrasB,
                                             int* __restrict__ c_valid,
                                             float* __restrict__ S,
                                             int* __restrict__ pcnt) {
    int blk = blockIdx.x;
    int c = blk >> 3;
    int t = threadIdx.x, lane = t & 63, wv = t >> 6;
    int cc = counts[c];
    int base = blk * 64;
    float sacc[4] = {0.f, 0.f, 0.f, 0.f};
    int vcnt = 0;

    for (int it = 0; it < 16; ++it) {
        int a = base + it * 4 + wv;
        int m = a & 511;
        float4 xv = *(const float4*)&xF[(size_t)a * DIM + lane * 4];
        float x[4] = {xv.x, xv.y, xv.z, xv.w};
        float ss = x[0]*x[0] + x[1]*x[1] + x[2]*x[2] + x[3]*x[3];
#pragma unroll
        for (int o = 1; o < 64; o <<= 1) ss += __shfl_xor(ss, o, 64);
        float scale = 1.0f / fmaxf(sqrtf(ss), 1e-12f);
        float ax[4];
#pragma unroll
        for (int q = 0; q < 4; ++q) ax[q] = x[q] * scale;
        short4 oa;
        oa.x = f2bf(ax[0]); oa.y = f2bf(ax[1]); oa.z = f2bf(ax[2]); oa.w = f2bf(ax[3]);
        *(short4*)&anchorsB[(size_t)a * DIM + lane * 4] = oa;

        bool upd = m < cc;
        float4 bv = *(const float4*)&bank[(size_t)a * DIM + lane * 4];
        float u[4];
        u[0] = upd ? 0.999f * bv.x + 0.001f * ax[0] : bv.x;
        u[1] = upd ? 0.999f * bv.y + 0.001f * ax[1] : bv.y;
        u[2] = upd ? 0.999f * bv.z + 0.001f * ax[2] : bv.z;
        u[3] = upd ? 0.999f * bv.w + 0.001f * ax[3] : bv.w;
        float ss2 = u[0]*u[0] + u[1]*u[1] + u[2]*u[2] + u[3]*u[3];
#pragma unroll
        for (int o = 1; o < 64; o <<= 1) ss2 += __shfl_xor(ss2, o, 64);
        float nrm = sqrtf(ss2);
        float inv = 1.0f / fmaxf(nrm, 1e-12f);
        short oc[4];
        oc[0] = f2bf(upd ? u[0] * inv : bv.x);
        oc[1] = f2bf(upd ? u[1] * inv : bv.y);
        oc[2] = f2bf(upd ? u[2] * inv : bv.z);
        oc[3] = f2bf(upd ? u[3] * inv : bv.w);
        *(short4*)&contrasB[(size_t)a * DIM + lane * 4] = *(short4*)oc;
        bool valid = nrm > 0.0f;
        if (lane == 0) {
            c_valid[a] = valid ? 1 : 0;
            vcnt += valid ? 1 : 0;
        }
        if (valid) {
#pragma unroll
            for (int q = 0; q < 4; ++q) sacc[q] += bf2f(oc[q]);
        }
    }

    __shared__ float s4[4][DIM];
    __shared__ int pv[4];
#pragma unroll
    for (int q = 0; q < 4; ++q) s4[wv][lane * 4 + q] = sacc[q];
    if (lane == 0) pv[wv] = vcnt;
    __syncthreads();
    float s = s4[0][t] + s4[1][t] + s4[2][t] + s4[3][t];
    atomicAdd(&S[c * DIM + t], s);
    if (t == 0) atomicAdd(&pcnt[c], pv[0] + pv[1] + pv[2] + pv[3]);
}

// ---------------- K5: bf16 MFMA scores + fused sum-exp ----------------
// 128x256 tile, 512 threads (8 waves 2x4, wave 64x64 via 4x4 mfma 16x16x32),
// BK=32 double-buffered (48KB LDS), acc=64 VGPR -> 4 waves/SIMD, 2 blocks/CU.
__global__ __launch_bounds__(512, 4) void k_score(const short* __restrict__ A,
                                                  const short* __restrict__ Bc,
                                                  const int* __restrict__ c_valid,
                                                  float* __restrict__ row_sumexp) {
    __shared__ short As[2][128 * 32];   // 8 KB each
    __shared__ short Bs[2][256 * 32];   // 16 KB each
    int t = threadIdx.x;
    int lane = t & 63, wv = t >> 6;
    int wr = wv & 1, wc = wv >> 1;        // wave tile: 64 rows x 64 cols
    int row0 = blockIdx.x * 128, col0 = blockIdx.y * 256;
    int lrow = lane >> 2;
    int gseg = (lane & 3) ^ (lrow & 3);   // swizzled global 16B segment
    int qr = lane >> 4, qc = lane & 15;

    f32x4 acc[4][4] = {};

    const short* Ag = A  + (size_t)row0 * DIM;
    const short* Bg = Bc + (size_t)col0 * DIM;

    auto stage = [&](int buf, int k0) {
        // A: 128 rows -> 8 waves x 16 rows (1 gld16 each)
        gld16(Ag + (size_t)(wv * 16 + lrow) * DIM + k0 + gseg * 8,
              &As[buf][(wv * 16) * 32]);
        // B: 256 rows -> 8 waves x 32 rows (2 gld16 each)
        gld16(Bg + (size_t)(wv * 32 + lrow) * DIM + k0 + gseg * 8,
              &Bs[buf][(wv * 32) * 32]);
        gld16(Bg + (size_t)(wv * 32 + 16 + lrow) * DIM + k0 + gseg * 8,
              &Bs[buf][(wv * 32 + 16) * 32]);
    };

    stage(0, 0);
#pragma unroll
    for (int k = 0; k < 8; ++k) {
        int cur = k & 1;
        if (k < 7) {
            stage(cur ^ 1, (k + 1) * 32);
            asm volatile("s_waitcnt vmcnt(3)" ::: "memory");   // this wave's current 3 landed
        } else {
            asm volatile("s_waitcnt vmcnt(0)" ::: "memory");
        }
        asm volatile("s_barrier" ::: "memory");

        bf16x8 af[4], bfv[4];
        int slot = (qr ^ (qc & 3)) * 8;
#pragma unroll
        for (int i = 0; i < 4; ++i)
            af[i] = *(const bf16x8*)&As[cur][(wr * 64 + i * 16 + qc) * 32 + slot];
#pragma unroll
        for (int j = 0; j < 4; ++j)
            bfv[j] = *(const bf16x8*)&Bs[cur][(wc * 64 + j * 16 + qc) * 32 + slot];
#pragma unroll
        for (int i = 0; i < 4; ++i)
#pragma unroll
            for (int j = 0; j < 4; ++j)
                acc[i][j] = __builtin_amdgcn_mfma_f32_16x16x32_bf16(af[i], bfv[j], acc[i][j], 0, 0, 0);

        if (k < 7) asm volatile("s_barrier" ::: "memory");
    }

    float cm[4];
#pragma unroll
    for (int j = 0; j < 4; ++j)
        cm[j] = c_valid[col0 + wc * 64 + j * 16 + qc] ? 1.0f : 0.0f;
#pragma unroll
    for (int i = 0; i < 4; ++i)
#pragma unroll
        for (int r = 0; r < 4; ++r) {
            float e = cm[0] * fexp2(acc[i][0][r] * EXP2K)
                    + cm[1] * fexp2(acc[i][1][r] * EXP2K)
                    + cm[2] * fexp2(acc[i][2][r] * EXP2K)
                    + cm[3] * fexp2(acc[i][3][r] * EXP2K);
#pragma unroll
            for (int o = 1; o < 16; o <<= 1) e += __shfl_xor(e, o, 64);
            if (qc == 0)
                atomicAdd(&row_sumexp[row0 + wr * 64 + i * 16 + qr * 4 + r], e);
        }
}

// ---------------- K6: per-row loss terms + last-block final reduction ----------------
// block = 64 rows (160 blocks); pos_sum = TEMP_INV * (anchor . S[class])
__global__ __launch_bounds__(256) void k_fin(const short* __restrict__ anchorsB,
                                             const float* __restrict__ S,
                                             const int* __restrict__ counts,
                                             const int* __restrict__ pcnt,
                                             const float* __restrict__ row_sumexp,
                                             float* __restrict__ facc,
                                             int* __restrict__ done_cnt,
                                             float* __restrict__ out) {
    int blk = blockIdx.x;
    int c = blk >> 3;
    int t = threadIdx.x, lane = t & 63, wv = t >> 6;
    int pc = pcnt[c], cc = counts[c];
    float lsum = 0.0f, vc = 0.0f;

    for (int it = 0; it < 16; ++it) {
        int a = blk * 64 + it * 4 + wv;
        short4 a4 = *(const short4*)&anchorsB[(size_t)a * DIM + lane * 4];
        float4 s4 = *(const float4*)&S[c * DIM + lane * 4];
        float dot = bf2f(a4.x) * s4.x + bf2f(a4.y) * s4.y
                  + bf2f(a4.z) * s4.z + bf2f(a4.w) * s4.w;
#pragma unroll
        for (int o = 1; o < 64; o <<= 1) dot += __shfl_xor(dot, o, 64);
        if (lane == 0 && (a & 511) < cc && pc > 0) {
            float lse = logf(row_sumexp[a]);
            lsum += (TEMP_INV * dot - (float)pc * lse) / (float)pc;
            vc += 1.0f;
        }
    }

    __shared__ float wls[4], wvc[4];
    if (lane == 0) { wls[wv] = lsum; wvc[wv] = vc; }
    __syncthreads();
    if (t == 0) {
        atomicAdd(&facc[0], wls[0] + wls[1] + wls[2] + wls[3]);
        atomicAdd(&facc[1], wvc[0] + wvc[1] + wvc[2] + wvc[3]);
        __threadfence();
        unsigned d = atomicAdd((unsigned*)done_cnt, 1u);
        if (d == 159u) {   // last block: totals are globally visible via atomics
            __threadfence();
            float L = atomicAdd(&facc[0], 0.0f);
            float V = atomicAdd(&facc[1], 0.0f);
            out[0] = -L / fmaxf(V, 1.0f);
        }
    }
}

// ---------------- launch ----------------
extern "C" void kernel_launch(void* const* d_in, const int* in_sizes, int n_in,
                              void* d_out, int out_size, void* d_ws, size_t ws_size,
                              hipStream_t stream) {
    const float* main_proj = (const float*)d_in[0];
    const int*   main_gt   = (const int*)d_in[1];
    const float* aux_proj  = (const float*)d_in[2];
    const int*   aux_gt    = (const int*)d_in[3];
    const float* bank      = (const float*)d_in[4];
    float* out = (float*)d_out;

    char* ws = (char*)d_ws;
    int*   labels     = (int*)ws;                    // 524288 B (dead after k_write)
    int*   hist       = (int*)(ws + 524288);         // 40960 B
    int*   pix2row    = (int*)(ws + 565248);         // 524288 B
    int*   c_valid    = (int*)(ws + 1089536);        // 40960 B
    float* zreg       = (float*)(ws + 1130496);      // 61952 B zero region
    float* row_sumexp = zreg;
    float* S          = zreg + 10240;
    int*   pcnt       = (int*)(zreg + 15360);
    float* facc       = zreg + 15380;
    int*   done_cnt   = (int*)(zreg + 15382);
    int*   counts     = (int*)(ws + 1192448);        // 256 B (written by k_write, no pre-zero)
    float* xF         = (float*)(ws + 1192704);      // 10485760 B
    short* anchorsB   = (short*)(ws + 11678464);     // 5242880 B
    short* contrasB   = (short*)(ws + 16921344);     // 5242880 B (end 22164224)

    k_hist<<<512, 256, 0, stream>>>(main_gt, aux_gt, labels, hist, pix2row, zreg);
    k_write<<<512, 256, 0, stream>>>(labels, hist, pix2row, counts);
    k_scatter<<<32768, 256, 0, stream>>>(main_proj, aux_proj, pix2row, xF);
    k_nbc<<<AROWS / 64, 256, 0, stream>>>(xF, bank, counts, anchorsB, contrasB,
                                          c_valid, S, pcnt);
    dim3 grid(AROWS / 128, AROWS / 256);
    k_score<<<grid, 512, 0, stream>>>(anchorsB, contrasB, c_valid, row_sumexp);
    k_fin<<<AROWS / 64, 256, 0, stream>>>(anchorsB, S, counts, pcnt, row_sumexp,
                                          facc, done_cnt, out);
}